// Round 5
// baseline (1038.539 us; speedup 1.0000x reference)
//
#include <hip/hip_runtime.h>
#include <hip/hip_bf16.h>

#define DD    1024
#define NROWS 3072
#define NLAY  17

typedef __attribute__((ext_vector_type(8))) short short8;
typedef __attribute__((ext_vector_type(4))) float floatx4;

// ---------------------------------------------------------------- convert + prep (fused)
__global__ __launch_bounds__(256) void convprep_kernel(
    const float* __restrict__ W0, const float* __restrict__ Ws,
    ushort* __restrict__ Wbf, const float* __restrict__ Xin,
    ushort* __restrict__ X0bf)
{
  if (blockIdx.x < 17408) {
    const size_t i4 = ((size_t)blockIdx.x * 256 + threadIdx.x) * 4;
    float4 v;
    if (i4 < 1048576) v = *(const float4*)(W0 + i4);
    else              v = *(const float4*)(Ws + (i4 - 1048576));
    union { __hip_bfloat16 h[4]; ushort u[4]; } pk;
    pk.h[0] = __float2bfloat16(v.x); pk.h[1] = __float2bfloat16(v.y);
    pk.h[2] = __float2bfloat16(v.z); pk.h[3] = __float2bfloat16(v.w);
    *(ushort4*)(Wbf + i4) = *(ushort4*)pk.u;
    return;
  }
  const int row = blockIdx.x - 17408;   // 0..3071  (= b*3 + c)
  const int c   = row % 3;
  const float* src = Xin + (size_t)row * DD;
  ushort* dst = X0bf + (size_t)row * DD;
  for (int t = threadIdx.x; t < DD; t += 256) {
    float v;
    if (c == 2) v = src[(t & 15) * 64 + (t >> 4)];
    else        v = src[t];
    __hip_bfloat16 h = __float2bfloat16(v);
    dst[t] = *(ushort*)&h;
  }
}

// ---------------------------------------------------------------- MFMA GEMM
// 128x64 tile (best LDS-read amortization at grid>=1.5 blocks/CU: 24 reads+12
// writes per 32 MFMA-units) + 2-phase double-buffered pipeline (stage t+1
// before computing t; one barrier per K-step, vmcnt drain lands after the
// compute phase). Grid 384 = 1.5 blocks/CU. Per-output K-accumulation order
// identical to prior rounds -> bit-identical results.
__global__ __launch_bounds__(256) void gemm_kernel(
    const ushort* __restrict__ Abf, const ushort* __restrict__ Wbf,
    const float* __restrict__ Xres, const float* __restrict__ bias,
    const float* __restrict__ hp, float* __restrict__ Y, int fuse)
{
  __shared__ __align__(16) ushort As[2][128 * 32];
  __shared__ __align__(16) ushort Bs[2][64 * 32];
  const int tid  = threadIdx.x;
  const int wave = tid >> 6, lane = tid & 63;

  // bijective XCD swizzle (384 % 8 == 0): 48 blocks/chunk
  const int id = blockIdx.x;
  const int w  = (id & 7) * 48 + (id >> 3);
  const int bm = (w >> 4) * 128;        // 24 M-tiles
  const int bn = (w & 15) * 64;         // 16 N-tiles

  // staging: lane -> (row=lane>>2, 16B col chunk=lane&3)
  const int srow = wave * 16 + (lane >> 2);
  const int scol = (lane & 3) * 8;
  const ushort* ga0 = Abf + (size_t)(bm + srow) * DD + scol;
  const ushort* gb0 = Wbf + (size_t)(bn + srow) * DD + scol;

  const int wm0 = (wave >> 1) * 64, wn0 = (wave & 1) * 32;
  const int m = lane & 15, quad = lane >> 4;

  floatx4 acc[4][2] = {};

  // prologue: stage tile 0 into buf 0
#pragma unroll
  for (int q = 0; q < 2; ++q)
    __builtin_amdgcn_global_load_lds(
        (const __attribute__((address_space(1))) unsigned int*)(ga0 + (size_t)q * 64 * DD),
        (__attribute__((address_space(3))) unsigned int*)&As[0][(q * 64 + wave * 16) * 32],
        16, 0, 0);
  __builtin_amdgcn_global_load_lds(
      (const __attribute__((address_space(1))) unsigned int*)(gb0),
      (__attribute__((address_space(3))) unsigned int*)&Bs[0][(wave * 16) * 32],
      16, 0, 0);
  __syncthreads();                      // vmcnt drained before barrier

  int cur = 0;
  for (int t = 0; t < 31; ++t) {
    const int k1 = (t + 1) * 32;
    // issue next-tile stage into buf^1 (all waves finished reading it before
    // the previous barrier)
#pragma unroll
    for (int q = 0; q < 2; ++q)
      __builtin_amdgcn_global_load_lds(
          (const __attribute__((address_space(1))) unsigned int*)(ga0 + (size_t)q * 64 * DD + k1),
          (__attribute__((address_space(3))) unsigned int*)&As[cur ^ 1][(q * 64 + wave * 16) * 32],
          16, 0, 0);
    __builtin_amdgcn_global_load_lds(
        (const __attribute__((address_space(1))) unsigned int*)(gb0 + k1),
        (__attribute__((address_space(3))) unsigned int*)&Bs[cur ^ 1][(wave * 16) * 32],
        16, 0, 0);
    // compute current tile
    short8 av[4], bv[2];
#pragma unroll
    for (int i = 0; i < 4; ++i)
      av[i] = *(const short8*)&As[cur][(wm0 + i * 16 + m) * 32 + quad * 8];
#pragma unroll
    for (int j = 0; j < 2; ++j)
      bv[j] = *(const short8*)&Bs[cur][(wn0 + j * 16 + m) * 32 + quad * 8];
#pragma unroll
    for (int i = 0; i < 4; ++i)
#pragma unroll
      for (int j = 0; j < 2; ++j)
        acc[i][j] = __builtin_amdgcn_mfma_f32_16x16x32_bf16(av[i], bv[j], acc[i][j], 0, 0, 0);
    __syncthreads();                    // drain staged loads; cur fully read
    cur ^= 1;
  }
  {
    // epilogue tile (no prefetch)
    short8 av[4], bv[2];
#pragma unroll
    for (int i = 0; i < 4; ++i)
      av[i] = *(const short8*)&As[cur][(wm0 + i * 16 + m) * 32 + quad * 8];
#pragma unroll
    for (int j = 0; j < 2; ++j)
      bv[j] = *(const short8*)&Bs[cur][(wn0 + j * 16 + m) * 32 + quad * 8];
#pragma unroll
    for (int i = 0; i < 4; ++i)
#pragma unroll
      for (int j = 0; j < 2; ++j)
        acc[i][j] = __builtin_amdgcn_mfma_f32_16x16x32_bf16(av[i], bv[j], acc[i][j], 0, 0, 0);
  }

  // epilogue: C layout col=lane&15, row=quad*4+reg
  const float h = fuse ? hp[0] : 0.0f;
#pragma unroll
  for (int i = 0; i < 4; ++i) {
#pragma unroll
    for (int r = 0; r < 4; ++r) {
      const int grow = bm + wm0 + i * 16 + quad * 4 + r;
      float* yr = Y + (size_t)grow * DD;
      const float* xr = Xres + (size_t)grow * DD;
#pragma unroll
      for (int j = 0; j < 2; ++j) {
        const int gcol = bn + wn0 + j * 16 + m;
        float d = acc[i][j][r];
        if (fuse) d = xr[gcol] + h * fmaxf(d + bias[gcol], 0.0f);
        yr[gcol] = d;
      }
    }
  }
}

// ---------------------------------------------------------------- projection
// One wave per block. Newton-Schulz entirely in MFMA fragments (see R3 notes).
__device__ __forceinline__ void split_wr(ushort* Bh, ushort* Bl, int c, int q, floatx4 a) {
  union { ushort u[4]; uint2 d; } ph, pl;
#pragma unroll
  for (int j = 0; j < 4; ++j) {
    const float x = a[j];
    __hip_bfloat16 hb = __float2bfloat16(x);
    const float hf = __bfloat162float(hb);
    __hip_bfloat16 lb = __float2bfloat16(x - hf);
    ph.u[j] = *(const ushort*)&hb;
    pl.u[j] = *(const ushort*)&lb;
  }
  *(uint2*)&Bh[c * 40 + q * 4] = ph.d;
  *(uint2*)&Bl[c * 40 + q * 4] = pl.d;
}

__global__ __launch_bounds__(64) void proj_kernel(
    const float* __restrict__ Yg, float* __restrict__ Xg,
    __hip_bfloat16* __restrict__ stage, int layer, int iters)
{
  __shared__ __align__(16) ushort POOL[5632];   // 11264 B unioned pool

  const int lane = threadIdx.x;                  // 0..63

  if (blockIdx.x >= 2048) {                      // ---- channel-1 copy path
    const int b = blockIdx.x - 2048;
    const int row = b * 3 + 1;
    const float* src = Yg + (size_t)row * DD + lane * 16;
    float* dst = Xg + (size_t)row * DD + lane * 16;
    float v[16];
#pragma unroll
    for (int q = 0; q < 4; ++q) {
      const float4 t4 = *(const float4*)(src + q * 4);
      v[q*4+0]=t4.x; v[q*4+1]=t4.y; v[q*4+2]=t4.z; v[q*4+3]=t4.w;
      *(float4*)(dst + q * 4) = t4;
    }
    union { __hip_bfloat16 hh[16]; uint4 u[2]; } pk;
#pragma unroll
    for (int j = 0; j < 16; ++j) pk.hh[j] = __float2bfloat16(v[j]);
    uint4* sd = (uint4*)(stage + ((size_t)layer * NROWS + row) * DD + lane * 16);
    sd[0] = pk.u[0]; sd[1] = pk.u[1];
    return;
  }

  const int p = blockIdx.x;              // 0..2047
  const int b = p >> 1;
  const int row = b * 3 + (p & 1) * 2;   // channel 0 or 2
  const float* src = Yg + (size_t)row * DD + lane * 16;

  float v[16];
#pragma unroll
  for (int q = 0; q < 4; ++q) {
    const float4 t4 = *(const float4*)(src + q * 4);
    v[q*4+0]=t4.x; v[q*4+1]=t4.y; v[q*4+2]=t4.z; v[q*4+3]=t4.w;
  }
  float nrm = 0.f;
#pragma unroll
  for (int j = 0; j < 16; ++j) nrm += v[j] * v[j];
#pragma unroll
  for (int o = 32; o > 0; o >>= 1) nrm += __shfl_xor(nrm, o, 64);
  const float s = rsqrtf(nrm + 1e-30f);
#pragma unroll
  for (int j = 0; j < 16; ++j) v[j] *= s;       // v = scaled A row

  ushort* ATl = POOL;                 // A^T bf16 [16][72]
  ushort* Bh  = POOL + 1152;          // relayout hi [16][40]
  ushort* Bl  = POOL + 1792;          // relayout lo
  const int fr = lane & 15, fq = lane >> 4;

#pragma unroll
  for (int j = 0; j < 16; ++j) {
    __hip_bfloat16 hb = __float2bfloat16(v[j]);
    ATl[j * 72 + lane] = *(const ushort*)&hb;
  }
  *(uint2*)&Bh[fr * 40 + 16 + fq * 4] = make_uint2(0u, 0u);
  *(uint2*)&Bl[fr * 40 + 16 + fq * 4] = make_uint2(0u, 0u);
  asm volatile("" ::: "memory");

  // ---- G = (sA)^T (sA) via 2x MFMA (K=64)
  short8 g1 = *(const short8*)&ATl[fr * 72 + fq * 8];
  short8 g2 = *(const short8*)&ATl[fr * 72 + 32 + fq * 8];
  floatx4 gacc = {};
  gacc = __builtin_amdgcn_mfma_f32_16x16x32_bf16(g1, g1, gacc, 0, 0, 0);
  gacc = __builtin_amdgcn_mfma_f32_16x16x32_bf16(g2, g2, gacc, 0, 0, 0);

  float ss = gacc[0]*gacc[0] + gacc[1]*gacc[1] + gacc[2]*gacc[2] + gacc[3]*gacc[3];
#pragma unroll
  for (int o = 32; o > 0; o >>= 1) ss += __shfl_xor(ss, o, 64);
  const float gf = rsqrtf(ss + 1e-30f);        // 1/||G||_F

  floatx4 yd;
#pragma unroll
  for (int j = 0; j < 4; ++j) yd[j] = gacc[j] * gf;
  split_wr(Bh, Bl, fr, fq, yd);
  asm volatile("" ::: "memory");
  short8 Yh = *(const short8*)&Bh[fr * 40 + fq * 8];
  short8 Yl = *(const short8*)&Bl[fr * 40 + fq * 8];
  short8 Zh, Zl;
#pragma unroll
  for (int d = 0; d < 8; ++d) {
    Zh[d] = (fr == fq * 8 + d) ? (short)0x3F80 : (short)0;
    Zl[d] = 0;
  }

  for (int it = 0; it < iters; ++it) {
    floatx4 wv = {};
    wv = __builtin_amdgcn_mfma_f32_16x16x32_bf16(Zh, Yh, wv, 0, 0, 0);
    wv = __builtin_amdgcn_mfma_f32_16x16x32_bf16(Zh, Yl, wv, 0, 0, 0);
    wv = __builtin_amdgcn_mfma_f32_16x16x32_bf16(Zl, Yh, wv, 0, 0, 0);
    floatx4 td;
#pragma unroll
    for (int j = 0; j < 4; ++j)
      td[j] = ((fq * 4 + j == fr) ? 1.5f : 0.f) - 0.5f * wv[j];
    split_wr(Bh, Bl, fr, fq, td);
    asm volatile("" ::: "memory");
    short8 Th = *(const short8*)&Bh[fr * 40 + fq * 8];
    short8 Tl = *(const short8*)&Bl[fr * 40 + fq * 8];
    floatx4 zd = {};
    zd = __builtin_amdgcn_mfma_f32_16x16x32_bf16(Zh, Th, zd, 0, 0, 0);
    zd = __builtin_amdgcn_mfma_f32_16x16x32_bf16(Zh, Tl, zd, 0, 0, 0);
    zd = __builtin_amdgcn_mfma_f32_16x16x32_bf16(Zl, Th, zd, 0, 0, 0);
    if (it < iters - 1) {
      floatx4 yn = {};
      yn = __builtin_amdgcn_mfma_f32_16x16x32_bf16(Yh, Th, yn, 0, 0, 0);
      yn = __builtin_amdgcn_mfma_f32_16x16x32_bf16(Yh, Tl, yn, 0, 0, 0);
      yn = __builtin_amdgcn_mfma_f32_16x16x32_bf16(Yl, Th, yn, 0, 0, 0);
      split_wr(Bh, Bl, fr, fq, yn);
      asm volatile("" ::: "memory");
      Yh = *(const short8*)&Bh[fr * 40 + fq * 8];
      Yl = *(const short8*)&Bl[fr * 40 + fq * 8];
    }
    split_wr(Bh, Bl, fr, fq, zd);
    asm volatile("" ::: "memory");
    Zh = *(const short8*)&Bh[fr * 40 + fq * 8];
    Zl = *(const short8*)&Bl[fr * 40 + fq * 8];
  }

  // ---- U = (v*sqrt(gf)) * Z via 4 chunks x 3 MFMA
  const float us = sqrtf(gf);
  asm volatile("" ::: "memory");
  ushort* Ah = POOL;           // [64][40] bf16 hi, cols 16..31 zero
  ushort* Al = POOL + 2560;    // lo
  {
    union { ushort u[16]; uint4 q4[2]; } rh, rl;
#pragma unroll
    for (int j = 0; j < 16; ++j) {
      const float x = v[j] * us;
      __hip_bfloat16 hb = __float2bfloat16(x);
      const float hf = __bfloat162float(hb);
      __hip_bfloat16 lb = __float2bfloat16(x - hf);
      rh.u[j] = *(const ushort*)&hb;
      rl.u[j] = *(const ushort*)&lb;
    }
    *(uint4*)&Ah[lane * 40]      = rh.q4[0];
    *(uint4*)&Ah[lane * 40 + 8]  = rh.q4[1];
    *(uint4*)&Al[lane * 40]      = rl.q4[0];
    *(uint4*)&Al[lane * 40 + 8]  = rl.q4[1];
    const uint4 zz = make_uint4(0u, 0u, 0u, 0u);
    *(uint4*)&Ah[lane * 40 + 16] = zz; *(uint4*)&Ah[lane * 40 + 24] = zz;
    *(uint4*)&Al[lane * 40 + 16] = zz; *(uint4*)&Al[lane * 40 + 24] = zz;
  }
  asm volatile("" ::: "memory");
  short8 ah[4], al[4];
#pragma unroll
  for (int m4 = 0; m4 < 4; ++m4) {
    ah[m4] = *(const short8*)&Ah[(m4 * 16 + fr) * 40 + fq * 8];
    al[m4] = *(const short8*)&Al[(m4 * 16 + fr) * 40 + fq * 8];
  }
  floatx4 um[4];
#pragma unroll
  for (int m4 = 0; m4 < 4; ++m4) {
    floatx4 a = {};
    a = __builtin_amdgcn_mfma_f32_16x16x32_bf16(ah[m4], Zh, a, 0, 0, 0);
    a = __builtin_amdgcn_mfma_f32_16x16x32_bf16(ah[m4], Zl, a, 0, 0, 0);
    a = __builtin_amdgcn_mfma_f32_16x16x32_bf16(al[m4], Zh, a, 0, 0, 0);
    um[m4] = a;
  }
  asm volatile("" ::: "memory");
  float* Ub = (float*)POOL;            // [64][20] f32
#pragma unroll
  for (int m4 = 0; m4 < 4; ++m4)
#pragma unroll
    for (int j = 0; j < 4; ++j)
      Ub[(m4 * 16 + fq * 4 + j) * 20 + fr] = um[m4][j];
  asm volatile("" ::: "memory");
  float up[16];
#pragma unroll
  for (int i = 0; i < 4; ++i) {
    const float4 t4 = *(const float4*)&Ub[lane * 20 + i * 4];
    up[i*4+0]=t4.x; up[i*4+1]=t4.y; up[i*4+2]=t4.z; up[i*4+3]=t4.w;
  }
  float* dst = Xg + (size_t)row * DD + lane * 16;
#pragma unroll
  for (int q = 0; q < 4; ++q)
    *(float4*)(dst + q*4) = make_float4(up[q*4], up[q*4+1], up[q*4+2], up[q*4+3]);
  union { __hip_bfloat16 hh[16]; uint4 u[2]; } pk;
#pragma unroll
  for (int j = 0; j < 16; ++j) pk.hh[j] = __float2bfloat16(up[j]);
  uint4* sd = (uint4*)(stage + ((size_t)layer * NROWS + row) * DD + lane * 16);
  sd[0] = pk.u[0]; sd[1] = pk.u[1];
}

// ---------------------------------------------------------------- tail (transpose + classify fused)
__global__ __launch_bounds__(256) void tail_kernel(
    const __hip_bfloat16* __restrict__ stage, float* __restrict__ outT,
    const float* __restrict__ X, const float* __restrict__ Wc,
    const float* __restrict__ bc, float* __restrict__ out)
{
  __shared__ __align__(16) float pool[7680];
  const int t = threadIdx.x;

  if (blockIdx.x < 12288) {                    // ---- transpose path
    float* buf = pool;                         // [256][18]
    const int row = blockIdx.x >> 2;           // 0..3071
    const int d0  = (blockIdx.x & 3) * 256;
    for (int l = 0; l < NLAY; ++l)
      buf[t * 18 + l] = __bfloat162float(stage[((size_t)l * NROWS + row) * DD + d0 + t]);
    __syncthreads();
    const size_t ob = (size_t)(row * DD + d0) * NLAY;
    for (int i = 0; i < NLAY; ++i) {
      const int idx = i * 256 + t;             // < 4352
      const int dd = idx / 17, ll = idx % 17;
      outT[ob + idx] = buf[dd * 18 + ll];
    }
    return;
  }

  // ---- classify path
  const int b = blockIdx.x - 12288;
  float* U = pool;               // 64*17
  float* S = U + 1088;           // 16*17
  float* V = S + 272;            // 64*17
  float* T = V + 1088;           // 64*17
  float* Z = T + 1088;           // 4096
  float* wsum = Z + 4096;        // 40
  const float* x0 = X + (size_t)(b*3+0) * DD;
  const float* x1 = X + (size_t)(b*3+1) * DD;
  const float* x2 = X + (size_t)(b*3+2) * DD;
  for (int e = t; e < 1024; e += 256) {
    const int i = e >> 4, j = e & 15;
    U[i*17+j] = x0[e];
    V[i*17+j] = x2[e];
  }
  { const int i = t >> 4, j = t & 15; if (t < 256) S[i*17+j] = x1[i*16+j]; }
  __syncthreads();
  for (int e = t; e < 1024; e += 256) {     // T = U @ S
    const int i = e >> 4, j = e & 15;
    float a = 0.f;
    for (int k = 0; k < 16; ++k) a = fmaf(U[i*17+k], S[k*17+j], a);
    T[i*17+j] = a;
  }
  __syncthreads();
  for (int e = t; e < 4096; e += 256) {     // Z = T @ V^T
    const int i = e >> 6, j = e & 63;
    float a = 0.f;
    for (int k = 0; k < 16; ++k) a = fmaf(T[i*17+k], V[j*17+k], a);
    Z[e] = a;
  }
  __syncthreads();
  float part[10] = {};
  for (int e = t; e < 4096; e += 256) {
    const float z = Z[e];
#pragma unroll
    for (int n = 0; n < 10; ++n) part[n] = fmaf(z, Wc[(size_t)n * 4096 + e], part[n]);
  }
#pragma unroll
  for (int n = 0; n < 10; ++n) {
#pragma unroll
    for (int off = 32; off > 0; off >>= 1) part[n] += __shfl_xor(part[n], off, 64);
  }
  if ((t & 63) == 0) {
#pragma unroll
    for (int n = 0; n < 10; ++n) wsum[(t >> 6) * 10 + n] = part[n];
  }
  __syncthreads();
  if (t == 0) {
    float logits[10];
#pragma unroll
    for (int n = 0; n < 10; ++n)
      logits[n] = wsum[0*10+n] + wsum[1*10+n] + wsum[2*10+n] + wsum[3*10+n] + bc[n];
    float mx = logits[0];
    for (int n = 1; n < 10; ++n) mx = fmaxf(mx, logits[n]);
    float ex[10], sm = 0.f;
    for (int n = 0; n < 10; ++n) { ex[n] = expf(logits[n] - mx); sm += ex[n]; }
    const float inv = 1.f / sm;
    for (int n = 0; n < 10; ++n) {
      out[b*10 + n] = ex[n] * inv;
      out[10240 + b*10 + n] = logits[n];
    }
  }
}

// ---------------------------------------------------------------- launch
extern "C" void kernel_launch(void* const* d_in, const int* in_sizes, int n_in,
                              void* d_out, int out_size, void* d_ws, size_t ws_size,
                              hipStream_t stream) {
  const float* Xin = (const float*)d_in[0];
  const float* hp  = (const float*)d_in[1];
  const float* W0  = (const float*)d_in[2];
  const float* Ws  = (const float*)d_in[3];
  const float* bs  = (const float*)d_in[4];
  const float* Wc  = (const float*)d_in[5];
  const float* bc  = (const float*)d_in[6];
  float* out = (float*)d_out;

  char* ws = (char*)d_ws;
  float* Xb = (float*)ws;
  float* Yb = Xb + (size_t)NROWS * DD;
  __hip_bfloat16* stage =
      (__hip_bfloat16*)(ws + 2 * (size_t)NROWS * DD * 4);
  ushort* X0bf = (ushort*)(ws + 2 * (size_t)NROWS * DD * 4
                              + (size_t)NLAY * NROWS * DD * 2);
  ushort* Wbf  = X0bf + (size_t)NROWS * DD;

  convprep_kernel<<<20480, 256, 0, stream>>>(W0, Ws, Wbf, Xin, X0bf);

  gemm_kernel<<<384, 256, 0, stream>>>(X0bf, Wbf, Xb, bs, hp, Yb, 0);
  proj_kernel<<<3072, 64, 0, stream>>>(Yb, Xb, stage, 0, 13);

  for (int l = 0; l < 16; ++l) {
    gemm_kernel<<<384, 256, 0, stream>>>(
        (const ushort*)(stage + (size_t)l * NROWS * DD),
        Wbf + (size_t)(l + 1) * DD * DD,
        Xb, bs + (size_t)l * DD, hp, Yb, 1);
    proj_kernel<<<3072, 64, 0, stream>>>(Yb, Xb, stage, l + 1, 9);
  }

  tail_kernel<<<13312, 256, 0, stream>>>(stage, out + 20480, Xb, Wc, bc, out);
}